// Round 13
// baseline (56.376 us; speedup 1.0000x reference)
//
#include <hip/hip_runtime.h>
#include <hip/hip_bf16.h>

#define ALPHA 0.2f
#define LOG2E 1.4426950408889634f

typedef __attribute__((ext_vector_type(8))) short bf16x8;
typedef __attribute__((ext_vector_type(4))) float f32x4;
typedef __attribute__((ext_vector_type(4))) int i32x4;

__device__ __forceinline__ int cvt_pk_bf16(float lo, float hi) {
    int r;
    asm("v_cvt_pk_bf16_f32 %0, %1, %2" : "=v"(r) : "v"(lo), "v"(hi));
    return r;
}

// async global->LDS, 16B per lane; LDS dest = wave-uniform base + lane*16
__device__ __forceinline__ void stage16(const void* g, void* l) {
    __builtin_amdgcn_global_load_lds(
        (const __attribute__((address_space(1))) void*)g,
        (__attribute__((address_space(3))) void*)l, 16, 0, 0);
}

// ---------------------------------------------------------------------------
// Kernel A (verified round-11, unchanged): Wh = h @ W (fp32), si2/sj2 scaled
// by log2e, Wh emitted PRE-FRAGMENTED for the MFMA B operand:
//   WhF[((b*64 + jc)*4 + ob)*512 + lane*8 + e] = bf16(Wh[j][o]),
//   j = jc*32 + (lane>>4)*8 + e, o = ob*16 + (lane&15)
// ---------------------------------------------------------------------------
__global__ __launch_bounds__(256) void gat_precompute(
    const float* __restrict__ h, const float* __restrict__ W,
    const float* __restrict__ a, unsigned short* __restrict__ WhF,
    float* __restrict__ si2, float* __restrict__ sj2)
{
    __shared__ float h_lds[32][128];
    __shared__ float wh_lds[32][65];   // +1 pad
    const int tid  = threadIdx.x;
    const int lane = tid & 63;
    const int wave = tid >> 6;
    const long long row0 = (long long)blockIdx.x * 32;

    {
        const float4* s4 = (const float4*)(h + row0 * 128);
        #pragma unroll
        for (int i = 0; i < 4; ++i) {
            int idx = tid + i * 256;
            float4 v = s4[idx];
            *(float4*)&h_lds[idx >> 5][(idx & 31) * 4] = v;
        }
    }
    __syncthreads();

    const float a1 = a[lane];
    const float a2 = a[64 + lane];
    float acc[8];
    #pragma unroll
    for (int r = 0; r < 8; ++r) acc[r] = 0.0f;

    for (int f = 0; f < 128; f += 4) {
        const float w0 = W[(f+0)*64 + lane];
        const float w1 = W[(f+1)*64 + lane];
        const float w2 = W[(f+2)*64 + lane];
        const float w3 = W[(f+3)*64 + lane];
        #pragma unroll
        for (int r = 0; r < 8; ++r) {
            const float4 hv = *(const float4*)&h_lds[wave*8 + r][f];
            acc[r] = fmaf(hv.x, w0, acc[r]);
            acc[r] = fmaf(hv.y, w1, acc[r]);
            acc[r] = fmaf(hv.z, w2, acc[r]);
            acc[r] = fmaf(hv.w, w3, acc[r]);
        }
    }

    #pragma unroll
    for (int r = 0; r < 8; ++r) {
        const int rr = wave*8 + r;
        wh_lds[rr][lane] = acc[r];
        float s1 = acc[r] * a1;
        float s2 = acc[r] * a2;
        #pragma unroll
        for (int off = 32; off > 0; off >>= 1) {
            s1 += __shfl_xor(s1, off);
            s2 += __shfl_xor(s2, off);
        }
        if (lane == 0) {
            si2[row0 + rr] = s1 * LOG2E;
            sj2[row0 + rr] = s2 * LOG2E;
        }
    }
    __syncthreads();

    // fragment write: tid = ob*64 + lane
    const long long b  = row0 >> 11;
    const int jcb  = (int)((row0 & 2047) >> 5);   // j-chunk within batch
    const int ob   = tid >> 6;
    const int ln   = tid & 63;
    const int ar   = ln & 15;
    const int gg   = ln >> 4;
    i32x4 pk;
    #pragma unroll
    for (int k = 0; k < 4; ++k)
        pk[k] = cvt_pk_bf16(wh_lds[gg*8 + 2*k    ][ob*16 + ar],
                            wh_lds[gg*8 + 2*k + 1][ob*16 + ar]);
    *(i32x4*)(WhF + ((b*64 + jcb)*4 + ob)*512 + ln*8) = pk;
}

// ---------------------------------------------------------------------------
// Kernel B: round-11 structure, occupancy doubled. 512-thread blocks, 8
// waves = private 256-j eighths, 8 dbuf steps of 32 j (half the barriers of
// round 11). Grid 1024 -> 4 blocks/CU, target 32 waves/CU for memory-level
// parallelism (the shared limiter across rounds 10-12).
//  - adj: global_load_lds staging, 2KB/wave/step (verified swizzle u^(r&7))
//  - Wh:  pre-fragmented global B-fragments, prefetched 1 step ahead in regs
//  - sj:  direct per-lane loads (L1-hot)
// p = exp2(max(Ci+sj, 0.2*sj+Di)) * (adj>0), fixed row max (lrelu monotone).
// ---------------------------------------------------------------------------
__global__ __launch_bounds__(512) void gat_attention(
    const int* __restrict__ adj, const unsigned short* __restrict__ WhF,
    const float* __restrict__ si2, const float* __restrict__ sj2,
    float* __restrict__ out)
{
    __shared__ char ldsbuf[33280];  // [2][8 wave][2KB] staging; epi: 32K+512B
    const int tid  = threadIdx.x;
    const int lane = tid & 63;
    const int wave = tid >> 6;                       // 0..7 (j-eighth)
    const int b    = blockIdx.x & 7;                 // batch -> XCD affinity
    const int i0   = (int)((blockIdx.x >> 3) << 4);  // 16-row i-tile
    const int arow = lane & 15;
    const int g    = lane >> 4;
    const long long bN = (long long)b * 2048;

    // ---- adj staging sources (pre-swizzled: slot pu holds unit pu^(r&7)) --
    const int* asrc0;
    const int* asrc1;
    {
        int r = lane >> 3;
        int u = (lane & 7) ^ (r & 7);
        asrc0 = adj + (bN + i0 + r)*2048 + wave*256 + u*4;
        int r2 = 8 + (lane >> 3);
        int u2 = (lane & 7) ^ (r2 & 7);
        asrc1 = adj + (bN + i0 + r2)*2048 + wave*256 + u2*4;
    }

    // ---- B-fragment base: wave's j-chunks are jc = wave*8 + st ----
    const unsigned short* fbase =
        WhF + ((long long)(b*64 + wave*8) * 4) * 512 + lane*8;

    // ---- per-batch sjmax (block-redundant, once) ----
    const float* sjb = sj2 + bN;
    float mx = -INFINITY;
    #pragma unroll 4
    for (int i = 0; i < 32; ++i) mx = fmaxf(mx, sjb[lane + i*64]);
    #pragma unroll
    for (int off = 32; off > 0; off >>= 1) mx = fmaxf(mx, __shfl_xor(mx, off));

    const float si_r = si2[bN + i0 + arow];        // P-row = arow
    const float u0f  = si_r + mx;
    const float m2   = fmaxf(u0f, ALPHA * u0f);    // fixed row max (log2 dom)
    const float Ci   = si_r - m2;
    const float Di   = ALPHA * si_r - m2;

    const float* sjq = sjb + wave*256 + g*8;       // this lane's sj stream

    f32x4 accf[4];
    #pragma unroll
    for (int ob = 0; ob < 4; ++ob) accf[ob] = (f32x4){0.f,0.f,0.f,0.f};
    f32x4 accl = (f32x4){0.f,0.f,0.f,0.f};
    bf16x8 ones;
    #pragma unroll
    for (int k = 0; k < 8; ++k) ones[k] = (short)0x3F80;   // bf16 1.0

    bf16x8 cb0, cb1, cb2, cb3, nb0, nb1, nb2, nb3;

    #define STAGE(S, STEP) { \
        char* base_ = ldsbuf + (S)*16384 + wave*2048; \
        stage16(asrc0 + (STEP)*32, base_); \
        stage16(asrc1 + (STEP)*32, base_ + 1024); \
    }

    #define LOADB(D0, D1, D2, D3, STEP) { \
        D0 = *(const bf16x8*)(fbase + ((STEP)*4 + 0)*512); \
        D1 = *(const bf16x8*)(fbase + ((STEP)*4 + 1)*512); \
        D2 = *(const bf16x8*)(fbase + ((STEP)*4 + 2)*512); \
        D3 = *(const bf16x8*)(fbase + ((STEP)*4 + 3)*512); \
    }

    #define BODY(S, STEP) { \
        const char* ab = ldsbuf + (S)*16384 + wave*2048; \
        const i32x4 A0 = *(const i32x4*)(ab + arow*128 + ((g*2    ) ^ (arow & 7))*16); \
        const i32x4 A1 = *(const i32x4*)(ab + arow*128 + ((g*2 + 1) ^ (arow & 7))*16); \
        const f32x4 S0 = *(const f32x4*)(sjq + (STEP)*32); \
        const f32x4 S1 = *(const f32x4*)(sjq + (STEP)*32 + 4); \
        float p[8]; \
        _Pragma("unroll") \
        for (int e = 0; e < 4; ++e) { \
            float pe = __builtin_amdgcn_exp2f( \
                fmaxf(Ci + S0[e], fmaf(ALPHA, S0[e], Di))); \
            p[e] = (A0[e] > 0) ? pe : 0.0f; \
        } \
        _Pragma("unroll") \
        for (int e = 0; e < 4; ++e) { \
            float pe = __builtin_amdgcn_exp2f( \
                fmaxf(Ci + S1[e], fmaf(ALPHA, S1[e], Di))); \
            p[4+e] = (A1[e] > 0) ? pe : 0.0f; \
        } \
        i32x4 pk_; \
        pk_[0] = cvt_pk_bf16(p[0], p[1]); \
        pk_[1] = cvt_pk_bf16(p[2], p[3]); \
        pk_[2] = cvt_pk_bf16(p[4], p[5]); \
        pk_[3] = cvt_pk_bf16(p[6], p[7]); \
        const bf16x8 pa = __builtin_bit_cast(bf16x8, pk_); \
        accl    = __builtin_amdgcn_mfma_f32_16x16x32_bf16(pa, ones, accl,    0, 0, 0); \
        accf[0] = __builtin_amdgcn_mfma_f32_16x16x32_bf16(pa, cb0, accf[0], 0, 0, 0); \
        accf[1] = __builtin_amdgcn_mfma_f32_16x16x32_bf16(pa, cb1, accf[1], 0, 0, 0); \
        accf[2] = __builtin_amdgcn_mfma_f32_16x16x32_bf16(pa, cb2, accf[2], 0, 0, 0); \
        accf[3] = __builtin_amdgcn_mfma_f32_16x16x32_bf16(pa, cb3, accf[3], 0, 0, 0); \
    }

    // ---- prologue ----
    STAGE(0, 0);
    LOADB(cb0, cb1, cb2, cb3, 0);
    __syncthreads();

    // ---- main loop: one barrier/step, 8 steps ----
    int s = 0;
    for (int st = 0; st < 7; ++st) {
        STAGE(s^1, st+1);
        LOADB(nb0, nb1, nb2, nb3, st+1);
        BODY(s, st);
        __syncthreads();
        cb0 = nb0; cb1 = nb1; cb2 = nb2; cb3 = nb3;
        s ^= 1;
    }
    BODY(s, 7);

    // ---- epilogue: combine the 8 j-eighth partials, divide, store ----
    __syncthreads();                          // all waves done with buffers
    float* accb = (float*)ldsbuf;             // [8 wave][16 i][64 o] = 32KB
    float* lb   = (float*)(ldsbuf + 32768);   // [8 wave][16 i]
    #pragma unroll
    for (int ob = 0; ob < 4; ++ob)
        #pragma unroll
        for (int reg = 0; reg < 4; ++reg)
            accb[(wave*16 + g*4 + reg)*64 + ob*16 + arow] = accf[ob][reg];
    if (arow == 0) {
        #pragma unroll
        for (int reg = 0; reg < 4; ++reg)
            lb[wave*16 + g*4 + reg] = accl[reg];
    }
    __syncthreads();

    const int r  = tid >> 5;                  // 0..15
    const int c0 = (tid & 31) * 2;            // 0..62
    float L = 0.f, s0 = 0.f, s1 = 0.f;
    #pragma unroll
    for (int w = 0; w < 8; ++w) {
        L  += lb[w*16 + r];
        s0 += accb[(w*16 + r)*64 + c0];
        s1 += accb[(w*16 + r)*64 + c0 + 1];
    }
    const float inv = 1.0f / L;
    *(float2*)(out + (bN + i0 + r)*64 + c0) = (float2){s0*inv, s1*inv};
}

// ---------------------------------------------------------------------------
// ws layout: WhF 2MB | si2 64KB | sj2 64KB
// ---------------------------------------------------------------------------
extern "C" void kernel_launch(void* const* d_in, const int* in_sizes, int n_in,
                              void* d_out, int out_size, void* d_ws, size_t ws_size,
                              hipStream_t stream) {
    const float* h   = (const float*)d_in[0];
    const int*   adj = (const int*)d_in[1];
    const float* W   = (const float*)d_in[2];
    const float* a   = (const float*)d_in[3];
    float* out = (float*)d_out;

    unsigned short* WhF = (unsigned short*)d_ws;                // 2 MB
    float* si2 = (float*)((char*)d_ws + (size_t)16384*64*2);
    float* sj2 = si2 + 16384;

    gat_precompute<<<256 * 2, 256, 0, stream>>>(h, W, a, WhF, si2, sj2);
    gat_attention<<<1024, 512, 0, stream>>>(adj, WhF, si2, sj2, out);
}